// Round 2
// baseline (111.452 us; speedup 1.0000x reference)
//
#include <hip/hip_runtime.h>

#define XDIM 40
#define VPR 10  // float4 blocks per row

// One thread = one full row of 40 states.
// - 10 coalesced float4 loads, 10 float4 stores per thread (1.0x traffic,
//   vs 3x load amplification in the per-float4-block version)
// - circular wrap handled by compile-time indices into a register array:
//   no div/mod, no conditional addressing, no redundant neighbor loads.
__global__ __launch_bounds__(256) void lorenz96_row_kernel(
    const float4* __restrict__ u4,
    const float* __restrict__ coeff,
    float4* __restrict__ out4,
    int rows) {
    int r = blockIdx.x * blockDim.x + threadIdx.x;
    if (r >= rows) return;   // rows = 262144 = 1024*256, never taken

    const float4* __restrict__ row  = u4   + (size_t)r * VPR;
    float4* __restrict__       orow = out4 + (size_t)r * VPR;

    // Load full row into registers. All indices compile-time after unroll.
    float a[XDIM];
    #pragma unroll
    for (int i = 0; i < VPR; ++i) {
        float4 b = row[i];
        a[4*i+0] = b.x; a[4*i+1] = b.y; a[4*i+2] = b.z; a[4*i+3] = b.w;
    }

    // coeff: uniform address -> scalar loads into SGPRs
    float c0  = coeff[0],  c1  = coeff[1],  c2  = coeff[2],  c3  = coeff[3];
    float c4  = coeff[4],  c5  = coeff[5],  c6  = coeff[6],  c7  = coeff[7];
    float c8  = coeff[8],  c9  = coeff[9],  c10 = coeff[10], c11 = coeff[11];
    float c12 = coeff[12], c13 = coeff[13], c14 = coeff[14], c15 = coeff[15];
    float c16 = coeff[16], c17 = coeff[17];

    #pragma unroll
    for (int i = 0; i < VPR; ++i) {
        float o[4];
        #pragma unroll
        for (int k = 0; k < 4; ++k) {
            const int idx = 4*i + k;
            const float um2 = a[(idx + XDIM - 2) % XDIM];  // compile-time index
            const float um1 = a[(idx + XDIM - 1) % XDIM];
            const float uc  = a[idx];
            const float up1 = a[(idx + 1) % XDIM];
            const float up2 = a[(idx + 2) % XDIM];
            // feats @ coeff, factored into 17 FMA:
            o[k] = c0
                + um2 * (c1 + c6  * um2 + c11 * um1 + c15 * uc)
                + um1 * (c2 + c7  * um1 + c12 * uc  + c16 * up1)
                + uc  * (c3 + c8  * uc  + c13 * up1 + c17 * up2)
                + up1 * (c4 + c9  * up1 + c14 * up2)
                + up2 * (c5 + c10 * up2);
        }
        float4 ov;
        ov.x = o[0]; ov.y = o[1]; ov.z = o[2]; ov.w = o[3];
        orow[i] = ov;
    }
}

extern "C" void kernel_launch(void* const* d_in, const int* in_sizes, int n_in,
                              void* d_out, int out_size, void* d_ws, size_t ws_size,
                              hipStream_t stream) {
    // d_in[0] = t (int scalar, unused)
    const float* u     = (const float*)d_in[1];
    const float* coeff = (const float*)d_in[2];
    float*       out   = (float*)d_out;

    // out_size is in ELEMENTS (floats), not bytes: 262144*40 = 10,485,760
    int rows   = out_size / XDIM;              // 262144
    int blocks = (rows + 255) / 256;           // 1024 blocks
    lorenz96_row_kernel<<<blocks, 256, 0, stream>>>(
        (const float4*)u, coeff, (float4*)out, rows);
}

// Round 3
// 96.263 us; speedup vs baseline: 1.1578x; 1.1578x over previous
//
#include <hip/hip_runtime.h>

#define XDIM 40
#define VPR 10  // float4 blocks per row

// Thread-per-float4-block layout: consecutive lanes access consecutive
// float4s -> perfectly coalesced loads AND stores (full 64B lines per
// instruction). The prv/nxt neighbor loads are L1/L2 hits (same lines
// adjacent lanes load as cen), so HBM traffic stays ~1x.
// Row-per-thread variant (160B lane stride) was tried and regressed:
// WRITE_SIZE 2x (partial-line sectors), kernel 9us -> 46us.
__global__ __launch_bounds__(256) void lorenz96_feats_kernel(
    const float4* __restrict__ u4,
    const float* __restrict__ coeff,
    float4* __restrict__ out4,
    int total_vec) {
    int v = blockIdx.x * blockDim.x + threadIdx.x;
    if (v >= total_vec) return;

    // row r = v / 10, float4-block-within-row p4 = v % 10
    unsigned int uv = (unsigned int)v;
    unsigned int r  = uv / VPR;
    unsigned int p4 = uv - r * VPR;

    const float4* row = u4 + (size_t)r * VPR;
    float4 cen = row[p4];
    float4 prv = row[p4 == 0        ? VPR - 1 : p4 - 1];
    float4 nxt = row[p4 == VPR - 1  ? 0       : p4 + 1];

    // a[j] = u[row, (4*p4 - 2 + j) mod 40], j = 0..7
    float a[8];
    a[0] = prv.z; a[1] = prv.w;
    a[2] = cen.x; a[3] = cen.y; a[4] = cen.z; a[5] = cen.w;
    a[6] = nxt.x; a[7] = nxt.y;

    // coeff: uniform address -> scalar loads into SGPRs
    float c0  = coeff[0],  c1  = coeff[1],  c2  = coeff[2],  c3  = coeff[3];
    float c4  = coeff[4],  c5  = coeff[5],  c6  = coeff[6],  c7  = coeff[7];
    float c8  = coeff[8],  c9  = coeff[9],  c10 = coeff[10], c11 = coeff[11];
    float c12 = coeff[12], c13 = coeff[13], c14 = coeff[14], c15 = coeff[15];
    float c16 = coeff[16], c17 = coeff[17];

    float o[4];
    #pragma unroll
    for (int k = 0; k < 4; ++k) {
        float um2 = a[k];
        float um1 = a[k + 1];
        float uc  = a[k + 2];
        float up1 = a[k + 3];
        float up2 = a[k + 4];
        // feats @ coeff, factored into 17 FMA:
        float val = c0
            + um2 * (c1 + c6 * um2 + c11 * um1 + c15 * uc)
            + um1 * (c2 + c7 * um1 + c12 * uc  + c16 * up1)
            + uc  * (c3 + c8 * uc  + c13 * up1 + c17 * up2)
            + up1 * (c4 + c9 * up1 + c14 * up2)
            + up2 * (c5 + c10 * up2);
        o[k] = val;
    }

    float4 ov;
    ov.x = o[0]; ov.y = o[1]; ov.z = o[2]; ov.w = o[3];
    out4[v] = ov;
}

extern "C" void kernel_launch(void* const* d_in, const int* in_sizes, int n_in,
                              void* d_out, int out_size, void* d_ws, size_t ws_size,
                              hipStream_t stream) {
    // d_in[0] = t (int scalar, unused)
    const float* u     = (const float*)d_in[1];
    const float* coeff = (const float*)d_in[2];
    float*       out   = (float*)d_out;

    int total_vec = out_size / 4;                 // 262144*40/4 = 2,621,440
    int blocks    = (total_vec + 255) / 256;      // 10,240 blocks
    lorenz96_feats_kernel<<<blocks, 256, 0, stream>>>(
        (const float4*)u, coeff, (float4*)out, total_vec);
}